// Round 1
// baseline (248.356 us; speedup 1.0000x reference)
//
#include <hip/hip_runtime.h>
#include <hip/hip_bf16.h>
#include <stdint.h>

// Problem constants (reference: B=8, S=2048, IN_F=OUT_F=2048, ORDER=3, RANK=4, LEAF=13)
#define MROWS 16384   // B*S
#define KDIM  2048    // IN_F
#define NDIM  2048    // OUT_F
#define LEAFD 13
#define RANKD 4

typedef __bf16 bf16x8 __attribute__((ext_vector_type(8)));
typedef float  f32x4  __attribute__((ext_vector_type(4)));

// ---------------------------------------------------------------------------
// Kernel 1: w_bf[o,i] = bf16( weight[o,i] + sum_r L0[r,o2,i2]*L1[r,o1,i1]*L2[r,o0,i0] )
// ---------------------------------------------------------------------------
__global__ void build_w_kernel(const float* __restrict__ weight,
                               const float* __restrict__ leaf,
                               __hip_bfloat16* __restrict__ wbf) {
    __shared__ float ll[3 * RANKD * LEAFD * LEAFD];  // 2028 floats
    for (int t = threadIdx.x; t < 3 * RANKD * LEAFD * LEAFD; t += blockDim.x)
        ll[t] = leaf[t];
    __syncthreads();
    int idx = blockIdx.x * blockDim.x + threadIdx.x;
    if (idx >= NDIM * KDIM) return;
    int o = idx / KDIM, i = idx % KDIM;
    int o2 = o / 169, o1 = (o / 13) % 13, o0 = o % 13;
    int i2 = i / 169, i1 = (i / 13) % 13, i0 = i % 13;
    float d = 0.f;
#pragma unroll
    for (int r = 0; r < RANKD; ++r) {
        float a = ll[( r            * LEAFD + o2) * LEAFD + i2];  // order 0
        float b = ll[((RANKD   + r) * LEAFD + o1) * LEAFD + i1];  // order 1
        float c = ll[((2*RANKD + r) * LEAFD + o0) * LEAFD + i0];  // order 2
        d += a * b * c;
    }
    wbf[idx] = __float2bfloat16(weight[idx] + d);
}

// ---------------------------------------------------------------------------
// Kernel 2: fp32 -> bf16 conversion of the activations (vectorized)
// ---------------------------------------------------------------------------
__global__ void cvt_kernel(const float* __restrict__ x,
                           __hip_bfloat16* __restrict__ xb, int n) {
    long stride = (long)gridDim.x * blockDim.x * 4;
    for (long idx = ((long)blockIdx.x * blockDim.x + threadIdx.x) * 4; idx < n; idx += stride) {
        float4 v = *reinterpret_cast<const float4*>(x + idx);
        __hip_bfloat16 tmp[4];
        tmp[0] = __float2bfloat16(v.x);
        tmp[1] = __float2bfloat16(v.y);
        tmp[2] = __float2bfloat16(v.z);
        tmp[3] = __float2bfloat16(v.w);
        *reinterpret_cast<uint2*>(xb + idx) = *reinterpret_cast<const uint2*>(tmp);
    }
}

// ---------------------------------------------------------------------------
// Kernel 3: C[m,n] = sum_k A[m,k]*W[n,k] + bias[n]   (bf16 in, fp32 out)
// m97 structure: 128x128 tile, BK=32, 4 waves (2x2), 16x16x32 MFMA,
// global_load_lds width-16 staging, linear LDS, 2 barriers per K-step.
// ---------------------------------------------------------------------------
#define BM 128
#define BN 128
#define BK 32

__device__ __forceinline__ void gload_lds16(const void* g, void* l) {
    __builtin_amdgcn_global_load_lds((const __attribute__((address_space(1))) void*)g,
                                     (__attribute__((address_space(3))) void*)l,
                                     16, 0, 0);
}

__global__ __launch_bounds__(256) void gemm_kernel(const __hip_bfloat16* __restrict__ A,
                                                   const __hip_bfloat16* __restrict__ Wb,
                                                   const float* __restrict__ bias,
                                                   float* __restrict__ C) {
    __shared__ __hip_bfloat16 sA[BM * BK];  // 8 KB
    __shared__ __hip_bfloat16 sB[BN * BK];  // 8 KB

    const int bid  = blockIdx.x;
    const int bn   = bid & 15;   // NDIM/BN == 16
    const int bm   = bid >> 4;
    const int tid  = threadIdx.x;
    const int lane = tid & 63;
    const int wid  = tid >> 6;         // 0..3
    const int wr   = wid >> 1;         // wave row (0..1)
    const int wc   = wid & 1;          // wave col (0..1)

    const size_t arow0 = (size_t)bm * BM;
    const size_t brow0 = (size_t)bn * BN;

    f32x4 acc[4][4];
#pragma unroll
    for (int m = 0; m < 4; ++m)
#pragma unroll
        for (int n = 0; n < 4; ++n)
            acc[m][n] = (f32x4){0.f, 0.f, 0.f, 0.f};

    const int rsel = lane & 15;
    const int ksel = (lane >> 4) * 8;

    for (int kt = 0; kt < KDIM / BK; ++kt) {
        const int k0 = kt * BK;
        // --- stage A and B tiles: 512 chunks of 16B each, linear LDS ---
#pragma unroll
        for (int j = 0; j < 2; ++j) {
            const int c   = (wid * 2 + j) * 64 + lane;   // chunk id 0..511
            const int row = c >> 2;
            const int ch  = c & 3;
            const __hip_bfloat16* ga = A  + (arow0 + row) * KDIM + k0 + ch * 8;
            const __hip_bfloat16* gb = Wb + (brow0 + row) * KDIM + k0 + ch * 8;
            gload_lds16(ga, &sA[(wid * 2 + j) * 512]);
            gload_lds16(gb, &sB[(wid * 2 + j) * 512]);
        }
        __syncthreads();   // compiler drains vmcnt before s_barrier

        // --- fragments: contiguous 8 bf16 along K -> one ds_read_b128 each ---
        bf16x8 af[4], bfr[4];
#pragma unroll
        for (int m = 0; m < 4; ++m)
            af[m] = *reinterpret_cast<const bf16x8*>(&sA[(wr * 64 + m * 16 + rsel) * BK + ksel]);
#pragma unroll
        for (int n = 0; n < 4; ++n)
            bfr[n] = *reinterpret_cast<const bf16x8*>(&sB[(wc * 64 + n * 16 + rsel) * BK + ksel]);

#pragma unroll
        for (int m = 0; m < 4; ++m)
#pragma unroll
            for (int n = 0; n < 4; ++n)
                acc[m][n] = __builtin_amdgcn_mfma_f32_16x16x32_bf16(af[m], bfr[n], acc[m][n], 0, 0, 0);

        __syncthreads();   // all reads done before next overwrite
    }

    // --- epilogue: C/D layout col = lane&15, row = (lane>>4)*4 + r ---
    const int col0 = lane & 15;
    const int r0   = (lane >> 4) * 4;
#pragma unroll
    for (int n = 0; n < 4; ++n) {
        const int cg = bn * BN + wc * 64 + n * 16 + col0;
        const float bv = bias[cg];
#pragma unroll
        for (int m = 0; m < 4; ++m) {
            const size_t rg = arow0 + wr * 64 + m * 16 + r0;
#pragma unroll
            for (int r = 0; r < 4; ++r)
                C[(rg + r) * NDIM + cg] = acc[m][n][r] + bv;
        }
    }
}

// ---------------------------------------------------------------------------
// Fallback (only if workspace is too small): naive fused fp32 GEMM. Slow but
// correct; not expected to run on this harness.
// ---------------------------------------------------------------------------
__global__ void naive_kernel(const float* __restrict__ x,
                             const float* __restrict__ leaf,
                             const float* __restrict__ W,
                             const float* __restrict__ bias,
                             float* __restrict__ out) {
    long idx = (long)blockIdx.x * blockDim.x + threadIdx.x;
    if (idx >= (long)MROWS * NDIM) return;
    int  o = (int)(idx % NDIM);
    long m = idx / NDIM;
    int o2 = o / 169, o1 = (o / 13) % 13, o0 = o % 13;
    float acc = 0.f;
    for (int i = 0; i < KDIM; ++i) {
        int i2 = i / 169, i1 = (i / 13) % 13, i0 = i % 13;
        float d = 0.f;
#pragma unroll
        for (int r = 0; r < RANKD; ++r)
            d += leaf[( r     * LEAFD + o2) * LEAFD + i2]
               * leaf[((4 + r) * LEAFD + o1) * LEAFD + i1]
               * leaf[((8 + r) * LEAFD + o0) * LEAFD + i0];
        acc += x[m * KDIM + i] * (W[(long)o * KDIM + i] + d);
    }
    out[idx] = acc + bias[o];
}

// ---------------------------------------------------------------------------
extern "C" void kernel_launch(void* const* d_in, const int* in_sizes, int n_in,
                              void* d_out, int out_size, void* d_ws, size_t ws_size,
                              hipStream_t stream) {
    const float* x      = (const float*)d_in[0];  // [8, 2048, 2048]
    const float* leaf   = (const float*)d_in[1];  // [3, 4, 13, 13]
    const float* weight = (const float*)d_in[2];  // [2048, 2048]
    const float* bias   = (const float*)d_in[3];  // [2048]
    float* out = (float*)d_out;                   // [8, 2048, 2048] fp32

    const size_t needA = (size_t)MROWS * KDIM * sizeof(__hip_bfloat16);  // 64 MiB
    const size_t needW = (size_t)NDIM  * KDIM * sizeof(__hip_bfloat16);  // 8 MiB

    if (ws_size >= needA + needW) {
        __hip_bfloat16* xb = (__hip_bfloat16*)d_ws;
        __hip_bfloat16* wb = (__hip_bfloat16*)((char*)d_ws + needA);
        build_w_kernel<<<(NDIM * KDIM + 255) / 256, 256, 0, stream>>>(weight, leaf, wb);
        cvt_kernel<<<2048, 256, 0, stream>>>(x, xb, MROWS * KDIM);
        gemm_kernel<<<(MROWS / BM) * (NDIM / BN), 256, 0, stream>>>(xb, wb, bias, out);
    } else {
        long total = (long)MROWS * NDIM;
        naive_kernel<<<(int)((total + 255) / 256), 256, 0, stream>>>(x, leaf, weight, bias, out);
    }
}

// Round 2
// 208.276 us; speedup vs baseline: 1.1924x; 1.1924x over previous
//
#include <hip/hip_runtime.h>
#include <hip/hip_bf16.h>
#include <stdint.h>

#define MROWS 16384   // B*S
#define KDIM  2048
#define NDIM  2048
#define LEAFD 13
#define RANKD 4

typedef __bf16 bf16x8 __attribute__((ext_vector_type(8)));
typedef float  f32x4  __attribute__((ext_vector_type(4)));

// ---------------------------------------------------------------------------
// Kernel 1: w_bf[o,i] = bf16( weight[o,i] + sum_r L0[r,o2,i2]*L1[r,o1,i1]*L2[r,o0,i0] )
// ---------------------------------------------------------------------------
__global__ void build_w_kernel(const float* __restrict__ weight,
                               const float* __restrict__ leaf,
                               __hip_bfloat16* __restrict__ wbf) {
    __shared__ float ll[3 * RANKD * LEAFD * LEAFD];
    for (int t = threadIdx.x; t < 3 * RANKD * LEAFD * LEAFD; t += blockDim.x)
        ll[t] = leaf[t];
    __syncthreads();
    int idx = blockIdx.x * blockDim.x + threadIdx.x;
    if (idx >= NDIM * KDIM) return;
    int o = idx / KDIM, i = idx % KDIM;
    int o2 = o / 169, o1 = (o / 13) % 13, o0 = o % 13;
    int i2 = i / 169, i1 = (i / 13) % 13, i0 = i % 13;
    float d = 0.f;
#pragma unroll
    for (int r = 0; r < RANKD; ++r) {
        float a = ll[( r            * LEAFD + o2) * LEAFD + i2];
        float b = ll[((RANKD   + r) * LEAFD + o1) * LEAFD + i1];
        float c = ll[((2*RANKD + r) * LEAFD + o0) * LEAFD + i0];
        d += a * b * c;
    }
    wbf[idx] = __float2bfloat16(weight[idx] + d);
}

// ---------------------------------------------------------------------------
// Kernel 2: fp32 -> bf16 conversion of activations
// ---------------------------------------------------------------------------
__global__ void cvt_kernel(const float* __restrict__ x,
                           __hip_bfloat16* __restrict__ xb, int n) {
    long stride = (long)gridDim.x * blockDim.x * 4;
    for (long idx = ((long)blockIdx.x * blockDim.x + threadIdx.x) * 4; idx < n; idx += stride) {
        float4 v = *reinterpret_cast<const float4*>(x + idx);
        __hip_bfloat16 tmp[4];
        tmp[0] = __float2bfloat16(v.x);
        tmp[1] = __float2bfloat16(v.y);
        tmp[2] = __float2bfloat16(v.z);
        tmp[3] = __float2bfloat16(v.w);
        *reinterpret_cast<uint2*>(xb + idx) = *reinterpret_cast<const uint2*>(tmp);
    }
}

// ---------------------------------------------------------------------------
// Kernel 3: 256x256x64 8-phase GEMM (T1+T2+T3+T4+T5), bf16 in fp32 out.
// C[m,n] = sum_k A[m,k]*W[n,k] + bias[n]
// 512 threads = 8 waves (2M x 4N); per-wave output 128x64.
// LDS: 2 bufs x 4 slots {A-klo, B-klo, A-khi, B-khi}, slot = 256 rows x 32 k.
// Staging runs 6 half-tiles (1.5 K-tiles) ahead; vmcnt(4) once per K-tile.
// Swizzle: 16B-chunk involution  c ^= (c>>3)&7  (byte: a ^= ((a>>7)&7)<<4),
// applied to the global SOURCE of global_load_lds (linear LDS dest) and to
// the ds_read address (both-sides rule).
// ---------------------------------------------------------------------------

__device__ __forceinline__ void gload16(const __hip_bfloat16* g, char* l) {
    __builtin_amdgcn_global_load_lds((const __attribute__((address_space(1))) void*)g,
                                     (__attribute__((address_space(3))) void*)l,
                                     16, 0, 0);
}

#define STAGE(base, kb, bufi, slot) do {                                          \
    gload16((base) + (kb) + gOff0, smemc + (bufi)*65536 + (slot)*16384 + lOff0);  \
    gload16((base) + (kb) + gOff1, smemc + (bufi)*65536 + (slot)*16384 + lOff1);  \
} while (0)

#define LOAD_A(mh, kk, bufc)                                                        \
    af0 = *(const bf16x8*)(smemc + (bufc)*65536 + (kk)*32768 + offA[(mh)*4+0]);     \
    af1 = *(const bf16x8*)(smemc + (bufc)*65536 + (kk)*32768 + offA[(mh)*4+1]);     \
    af2 = *(const bf16x8*)(smemc + (bufc)*65536 + (kk)*32768 + offA[(mh)*4+2]);     \
    af3 = *(const bf16x8*)(smemc + (bufc)*65536 + (kk)*32768 + offA[(mh)*4+3]);

#define LOAD_B(kk, bufc)                                                                    \
    bf0 = *(const bf16x8*)(smemc + (bufc)*65536 + (kk)*32768 + 16384 + offB[0]);            \
    bf1 = *(const bf16x8*)(smemc + (bufc)*65536 + (kk)*32768 + 16384 + offB[1]);            \
    bf2 = *(const bf16x8*)(smemc + (bufc)*65536 + (kk)*32768 + 16384 + offB[2]);            \
    bf3 = *(const bf16x8*)(smemc + (bufc)*65536 + (kk)*32768 + 16384 + offB[3]);

#define MFMA_Q(mh) do {                                                                   \
    acc[(mh)*4+0][0] = __builtin_amdgcn_mfma_f32_16x16x32_bf16(af0, bf0, acc[(mh)*4+0][0], 0,0,0); \
    acc[(mh)*4+1][0] = __builtin_amdgcn_mfma_f32_16x16x32_bf16(af1, bf0, acc[(mh)*4+1][0], 0,0,0); \
    acc[(mh)*4+2][0] = __builtin_amdgcn_mfma_f32_16x16x32_bf16(af2, bf0, acc[(mh)*4+2][0], 0,0,0); \
    acc[(mh)*4+3][0] = __builtin_amdgcn_mfma_f32_16x16x32_bf16(af3, bf0, acc[(mh)*4+3][0], 0,0,0); \
    acc[(mh)*4+0][1] = __builtin_amdgcn_mfma_f32_16x16x32_bf16(af0, bf1, acc[(mh)*4+0][1], 0,0,0); \
    acc[(mh)*4+1][1] = __builtin_amdgcn_mfma_f32_16x16x32_bf16(af1, bf1, acc[(mh)*4+1][1], 0,0,0); \
    acc[(mh)*4+2][1] = __builtin_amdgcn_mfma_f32_16x16x32_bf16(af2, bf1, acc[(mh)*4+2][1], 0,0,0); \
    acc[(mh)*4+3][1] = __builtin_amdgcn_mfma_f32_16x16x32_bf16(af3, bf1, acc[(mh)*4+3][1], 0,0,0); \
    acc[(mh)*4+0][2] = __builtin_amdgcn_mfma_f32_16x16x32_bf16(af0, bf2, acc[(mh)*4+0][2], 0,0,0); \
    acc[(mh)*4+1][2] = __builtin_amdgcn_mfma_f32_16x16x32_bf16(af1, bf2, acc[(mh)*4+1][2], 0,0,0); \
    acc[(mh)*4+2][2] = __builtin_amdgcn_mfma_f32_16x16x32_bf16(af2, bf2, acc[(mh)*4+2][2], 0,0,0); \
    acc[(mh)*4+3][2] = __builtin_amdgcn_mfma_f32_16x16x32_bf16(af3, bf2, acc[(mh)*4+3][2], 0,0,0); \
    acc[(mh)*4+0][3] = __builtin_amdgcn_mfma_f32_16x16x32_bf16(af0, bf3, acc[(mh)*4+0][3], 0,0,0); \
    acc[(mh)*4+1][3] = __builtin_amdgcn_mfma_f32_16x16x32_bf16(af1, bf3, acc[(mh)*4+1][3], 0,0,0); \
    acc[(mh)*4+2][3] = __builtin_amdgcn_mfma_f32_16x16x32_bf16(af2, bf3, acc[(mh)*4+2][3], 0,0,0); \
    acc[(mh)*4+3][3] = __builtin_amdgcn_mfma_f32_16x16x32_bf16(af3, bf3, acc[(mh)*4+3][3], 0,0,0); \
} while (0)

#define BARRIER_IN do {                                     \
    __builtin_amdgcn_sched_barrier(0);                      \
    __builtin_amdgcn_s_barrier();                           \
    asm volatile("s_waitcnt lgkmcnt(0)" ::: "memory");      \
    __builtin_amdgcn_sched_barrier(0);                      \
    __builtin_amdgcn_s_setprio(1);                          \
} while (0)

#define BARRIER_OUT do {                                    \
    __builtin_amdgcn_s_setprio(0);                          \
    __builtin_amdgcn_sched_barrier(0);                      \
    __builtin_amdgcn_s_barrier();                           \
    __builtin_amdgcn_sched_barrier(0);                      \
} while (0)

#define WAIT4 asm volatile("s_waitcnt vmcnt(4)" ::: "memory")
#define WAIT0 asm volatile("s_waitcnt vmcnt(0)" ::: "memory")
#define WNONE do {} while (0)

// One K-tile = 4 phases. Phase p: {ds_reads | stage half-tile | (wait)} barrier,
// lgkmcnt(0), setprio, 16 MFMA, setprio, barrier.
// Stage schedule: p0 -> tile t+1 A-khi (buf^1 slot2), p1 -> t+1 B-khi (buf^1 slot3),
//                 p2 -> tile t+2 A-klo (buf slot0),   p3 -> t+2 B-klo (buf slot1).
#define KTILE(t, bufc, S0, S1, S2, S3, W3) do {                     \
    /* p0: (mh0,k0) */                                              \
    LOAD_B(0, bufc); LOAD_A(0, 0, bufc);                            \
    if (S0) STAGE(Abase, ((t)+1)*64+32, (bufc)^1, 2);               \
    BARRIER_IN; MFMA_Q(0); BARRIER_OUT;                             \
    /* p1: (mh1,k0) */                                              \
    LOAD_A(1, 0, bufc);                                             \
    if (S1) STAGE(Bbase, ((t)+1)*64+32, (bufc)^1, 3);               \
    BARRIER_IN; MFMA_Q(1); BARRIER_OUT;                             \
    /* p2: (mh0,k1) */                                              \
    LOAD_B(1, bufc); LOAD_A(0, 1, bufc);                            \
    if (S2) STAGE(Abase, ((t)+2)*64, (bufc), 0);                    \
    BARRIER_IN; MFMA_Q(0); BARRIER_OUT;                             \
    /* p3: (mh1,k1) */                                              \
    LOAD_A(1, 1, bufc);                                             \
    if (S3) STAGE(Bbase, ((t)+2)*64, (bufc), 1);                    \
    W3;                                                             \
    BARRIER_IN; MFMA_Q(1); BARRIER_OUT;                             \
} while (0)

__global__ __launch_bounds__(512, 2) void gemm8_kernel(const __hip_bfloat16* __restrict__ A,
                                                       const __hip_bfloat16* __restrict__ Wb,
                                                       const float* __restrict__ bias,
                                                       float* __restrict__ C) {
    __shared__ __align__(16) __hip_bfloat16 smem[2][4][8192];  // 128 KiB
    char* smemc = (char*)&smem[0][0][0];

    const int tid  = threadIdx.x;
    const int lane = tid & 63;
    const int wid  = tid >> 6;        // 0..7
    const int wr   = wid >> 2;        // 0..1  (M half)
    const int wc   = wid & 3;         // 0..3  (N quarter)

    // T1: XCD-aware swizzle (nwg=512, 512%8==0 -> bijective). Each XCD owns one
    // 1 MB B column-panel (L2-resident); A streams through L3.
    const int bid = blockIdx.x;
    const int swz = (bid & 7) * 64 + (bid >> 3);
    const int bn  = swz >> 6;         // 0..7
    const int bm  = swz & 63;         // 0..63

    const __hip_bfloat16* Abase = A  + (size_t)bm * 256 * KDIM;
    const __hip_bfloat16* Bbase = Wb + (size_t)bn * 256 * KDIM;

    // --- staging source offsets (inverse-swizzled global, linear LDS dest) ---
    const int c0  = wid * 64 + lane;
    const int c1  = 512 + wid * 64 + lane;
    const int cs0 = c0 ^ ((c0 >> 3) & 7);
    const int cs1 = c1 ^ ((c1 >> 3) & 7);
    const int gOff0 = (cs0 >> 2) * KDIM + (cs0 & 3) * 8;   // elements
    const int gOff1 = (cs1 >> 2) * KDIM + (cs1 & 3) * 8;
    const int lOff0 = wid * 1024;                          // bytes (wave-uniform)
    const int lOff1 = 8192 + wid * 1024;

    // --- swizzled ds_read byte offsets within a 16 KB slot ---
    const int rsel = lane & 15;
    const int kby  = (lane >> 4) * 16;
    int offA[8], offB[4];
#pragma unroll
    for (int m = 0; m < 8; ++m) {
        int a = (wr * 128 + m * 16 + rsel) * 64 + kby;
        offA[m] = a ^ (((a >> 7) & 7) << 4);
    }
#pragma unroll
    for (int n = 0; n < 4; ++n) {
        int a = (wc * 64 + n * 16 + rsel) * 64 + kby;
        offB[n] = a ^ (((a >> 7) & 7) << 4);
    }

    f32x4 acc[8][4];
#pragma unroll
    for (int m = 0; m < 8; ++m)
#pragma unroll
        for (int n = 0; n < 4; ++n)
            acc[m][n] = (f32x4){0.f, 0.f, 0.f, 0.f};

    bf16x8 af0, af1, af2, af3, bf0, bf1, bf2, bf3;

    // --- prologue: stage 6 half-tiles (tile0 all 4 slots + tile1 slots 0,1) ---
    STAGE(Abase,  0, 0, 0);   // h0: t0 A-klo
    STAGE(Bbase,  0, 0, 1);   // h1: t0 B-klo
    STAGE(Abase, 32, 0, 2);   // h2: t0 A-khi
    STAGE(Bbase, 32, 0, 3);   // h3: t0 B-khi
    STAGE(Abase, 64, 1, 0);   // h4: t1 A-klo
    STAGE(Bbase, 64, 1, 1);   // h5: t1 B-klo
    WAIT4;                    // tile0 fully landed; h4,h5 may stay in flight
    __builtin_amdgcn_sched_barrier(0);
    __builtin_amdgcn_s_barrier();
    __builtin_amdgcn_sched_barrier(0);

    // --- main loop: KDIM/64 = 32 K-tiles, 2 per iteration ---
    for (int tt = 0; tt < 30; tt += 2) {
        KTILE(tt,     0, 1, 1, 1, 1, WAIT4);
        KTILE(tt + 1, 1, 1, 1, 1, 1, WAIT4);
    }
    KTILE(30, 0, 1, 1, 0, 0, WAIT0);   // stages h126,h127 (tile31 khi); drain
    KTILE(31, 1, 0, 0, 0, 0, WNONE);

    // --- epilogue: C/D layout col = lane&15, row = (lane>>4)*4 + r ---
    const int col0 = lane & 15;
    const int r0   = (lane >> 4) * 4;
#pragma unroll
    for (int n = 0; n < 4; ++n) {
        const int cg = bn * 256 + wc * 64 + n * 16 + col0;
        const float bv = bias[cg];
#pragma unroll
        for (int m = 0; m < 8; ++m) {
            const size_t rg = (size_t)bm * 256 + wr * 128 + m * 16 + r0;
#pragma unroll
            for (int r = 0; r < 4; ++r)
                C[(rg + r) * NDIM + cg] = acc[m][n][r] + bv;
        }
    }
}

// ---------------------------------------------------------------------------
// Fallback: naive fused fp32 GEMM (only if workspace too small).
// ---------------------------------------------------------------------------
__global__ void naive_kernel(const float* __restrict__ x,
                             const float* __restrict__ leaf,
                             const float* __restrict__ W,
                             const float* __restrict__ bias,
                             float* __restrict__ out) {
    long idx = (long)blockIdx.x * blockDim.x + threadIdx.x;
    if (idx >= (long)MROWS * NDIM) return;
    int  o = (int)(idx % NDIM);
    long m = idx / NDIM;
    int o2 = o / 169, o1 = (o / 13) % 13, o0 = o % 13;
    float acc = 0.f;
    for (int i = 0; i < KDIM; ++i) {
        int i2 = i / 169, i1 = (i / 13) % 13, i0 = i % 13;
        float d = 0.f;
#pragma unroll
        for (int r = 0; r < RANKD; ++r)
            d += leaf[( r     * LEAFD + o2) * LEAFD + i2]
               * leaf[((4 + r) * LEAFD + o1) * LEAFD + i1]
               * leaf[((8 + r) * LEAFD + o0) * LEAFD + i0];
        acc += x[m * KDIM + i] * (W[(long)o * KDIM + i] + d);
    }
    out[idx] = acc + bias[o];
}

// ---------------------------------------------------------------------------
extern "C" void kernel_launch(void* const* d_in, const int* in_sizes, int n_in,
                              void* d_out, int out_size, void* d_ws, size_t ws_size,
                              hipStream_t stream) {
    const float* x      = (const float*)d_in[0];
    const float* leaf   = (const float*)d_in[1];
    const float* weight = (const float*)d_in[2];
    const float* bias   = (const float*)d_in[3];
    float* out = (float*)d_out;

    const size_t needA = (size_t)MROWS * KDIM * sizeof(__hip_bfloat16);  // 64 MiB
    const size_t needW = (size_t)NDIM  * KDIM * sizeof(__hip_bfloat16);  // 8 MiB

    if (ws_size >= needA + needW) {
        __hip_bfloat16* xb = (__hip_bfloat16*)d_ws;
        __hip_bfloat16* wb = (__hip_bfloat16*)((char*)d_ws + needA);
        build_w_kernel<<<(NDIM * KDIM + 255) / 256, 256, 0, stream>>>(weight, leaf, wb);
        cvt_kernel<<<2048, 256, 0, stream>>>(x, xb, MROWS * KDIM);
        gemm8_kernel<<<(MROWS / 256) * (NDIM / 256), 512, 0, stream>>>(xb, wb, bias, out);
    } else {
        long total = (long)MROWS * NDIM;
        naive_kernel<<<(int)((total + 255) / 256), 256, 0, stream>>>(x, leaf, weight, bias, out);
    }
}

// Round 3
// 206.858 us; speedup vs baseline: 1.2006x; 1.0069x over previous
//
#include <hip/hip_runtime.h>
#include <hip/hip_bf16.h>
#include <stdint.h>

#define MROWS 16384   // B*S
#define KDIM  2048
#define NDIM  2048
#define LEAFD 13
#define RANKD 4

typedef __bf16 bf16x8 __attribute__((ext_vector_type(8)));
typedef float  f32x4  __attribute__((ext_vector_type(4)));

// ---------------------------------------------------------------------------
// Kernel 1: w_bf[o,i] = bf16( weight[o,i] + sum_r L0[r,o2,i2]*L1[r,o1,i1]*L2[r,o0,i0] )
// ---------------------------------------------------------------------------
__global__ void build_w_kernel(const float* __restrict__ weight,
                               const float* __restrict__ leaf,
                               __hip_bfloat16* __restrict__ wbf) {
    __shared__ float ll[3 * RANKD * LEAFD * LEAFD];
    for (int t = threadIdx.x; t < 3 * RANKD * LEAFD * LEAFD; t += blockDim.x)
        ll[t] = leaf[t];
    __syncthreads();
    int idx = blockIdx.x * blockDim.x + threadIdx.x;
    if (idx >= NDIM * KDIM) return;
    int o = idx / KDIM, i = idx % KDIM;
    int o2 = o / 169, o1 = (o / 13) % 13, o0 = o % 13;
    int i2 = i / 169, i1 = (i / 13) % 13, i0 = i % 13;
    float d = 0.f;
#pragma unroll
    for (int r = 0; r < RANKD; ++r) {
        float a = ll[( r            * LEAFD + o2) * LEAFD + i2];
        float b = ll[((RANKD   + r) * LEAFD + o1) * LEAFD + i1];
        float c = ll[((2*RANKD + r) * LEAFD + o0) * LEAFD + i0];
        d += a * b * c;
    }
    wbf[idx] = __float2bfloat16(weight[idx] + d);
}

// ---------------------------------------------------------------------------
// Kernel 2: fp32 -> bf16 conversion of activations (8 floats/thread)
// ---------------------------------------------------------------------------
__global__ void cvt_kernel(const float* __restrict__ x,
                           __hip_bfloat16* __restrict__ xb, int n) {
    long stride = (long)gridDim.x * blockDim.x * 8;
    for (long idx = ((long)blockIdx.x * blockDim.x + threadIdx.x) * 8; idx < n; idx += stride) {
        float4 v0 = *reinterpret_cast<const float4*>(x + idx);
        float4 v1 = *reinterpret_cast<const float4*>(x + idx + 4);
        __hip_bfloat16 tmp[8];
        tmp[0] = __float2bfloat16(v0.x); tmp[1] = __float2bfloat16(v0.y);
        tmp[2] = __float2bfloat16(v0.z); tmp[3] = __float2bfloat16(v0.w);
        tmp[4] = __float2bfloat16(v1.x); tmp[5] = __float2bfloat16(v1.y);
        tmp[6] = __float2bfloat16(v1.z); tmp[7] = __float2bfloat16(v1.w);
        *reinterpret_cast<uint4*>(xb + idx) = *reinterpret_cast<const uint4*>(tmp);
    }
}

// ---------------------------------------------------------------------------
// Kernel 3: 256x256x64 8-phase GEMM (T1+T2+T3+T4+T5), bf16 in fp32 out.
// 512 threads = 8 waves (2M x 4N); per-wave output 128x64.
// LDS: 2 bufs x 4 slots {A-klo, B-klo, A-khi, B-khi}, slot = 256 rows x 32 k.
// T4-deep: two vmcnt(8) waits per K-tile (p1-end covers p2; p3-end covers
// next p0). Every wait's required loads were issued 8 phases (~2000 cyc)
// earlier -> HBM latency fully hidden. In-flight <= 12 loads (6 half-tiles).
// Swizzle: byte involution a ^= ((a>>7)&7)<<4 applied to the global SOURCE of
// global_load_lds (linear LDS dest) and to the ds_read address (both sides).
// ---------------------------------------------------------------------------

__device__ __forceinline__ void gload16(const __hip_bfloat16* g, char* l) {
    __builtin_amdgcn_global_load_lds((const __attribute__((address_space(1))) void*)g,
                                     (__attribute__((address_space(3))) void*)l,
                                     16, 0, 0);
}

#define STAGE(base, kb, bufi, slot) do {                                          \
    gload16((base) + (kb) + gOff0, smemc + (bufi)*65536 + (slot)*16384 + lOff0);  \
    gload16((base) + (kb) + gOff1, smemc + (bufi)*65536 + (slot)*16384 + lOff1);  \
} while (0)

#define LOAD_A(mh, kk, bufc)                                                        \
    af0 = *(const bf16x8*)(smemc + (bufc)*65536 + (kk)*32768 + offA[(mh)*4+0]);     \
    af1 = *(const bf16x8*)(smemc + (bufc)*65536 + (kk)*32768 + offA[(mh)*4+1]);     \
    af2 = *(const bf16x8*)(smemc + (bufc)*65536 + (kk)*32768 + offA[(mh)*4+2]);     \
    af3 = *(const bf16x8*)(smemc + (bufc)*65536 + (kk)*32768 + offA[(mh)*4+3]);

#define LOAD_B(kk, bufc)                                                                    \
    bf0 = *(const bf16x8*)(smemc + (bufc)*65536 + (kk)*32768 + 16384 + offB[0]);            \
    bf1 = *(const bf16x8*)(smemc + (bufc)*65536 + (kk)*32768 + 16384 + offB[1]);            \
    bf2 = *(const bf16x8*)(smemc + (bufc)*65536 + (kk)*32768 + 16384 + offB[2]);            \
    bf3 = *(const bf16x8*)(smemc + (bufc)*65536 + (kk)*32768 + 16384 + offB[3]);

#define MFMA_Q(mh) do {                                                                   \
    acc[(mh)*4+0][0] = __builtin_amdgcn_mfma_f32_16x16x32_bf16(af0, bf0, acc[(mh)*4+0][0], 0,0,0); \
    acc[(mh)*4+1][0] = __builtin_amdgcn_mfma_f32_16x16x32_bf16(af1, bf0, acc[(mh)*4+1][0], 0,0,0); \
    acc[(mh)*4+2][0] = __builtin_amdgcn_mfma_f32_16x16x32_bf16(af2, bf0, acc[(mh)*4+2][0], 0,0,0); \
    acc[(mh)*4+3][0] = __builtin_amdgcn_mfma_f32_16x16x32_bf16(af3, bf0, acc[(mh)*4+3][0], 0,0,0); \
    acc[(mh)*4+0][1] = __builtin_amdgcn_mfma_f32_16x16x32_bf16(af0, bf1, acc[(mh)*4+0][1], 0,0,0); \
    acc[(mh)*4+1][1] = __builtin_amdgcn_mfma_f32_16x16x32_bf16(af1, bf1, acc[(mh)*4+1][1], 0,0,0); \
    acc[(mh)*4+2][1] = __builtin_amdgcn_mfma_f32_16x16x32_bf16(af2, bf1, acc[(mh)*4+2][1], 0,0,0); \
    acc[(mh)*4+3][1] = __builtin_amdgcn_mfma_f32_16x16x32_bf16(af3, bf1, acc[(mh)*4+3][1], 0,0,0); \
    acc[(mh)*4+0][2] = __builtin_amdgcn_mfma_f32_16x16x32_bf16(af0, bf2, acc[(mh)*4+0][2], 0,0,0); \
    acc[(mh)*4+1][2] = __builtin_amdgcn_mfma_f32_16x16x32_bf16(af1, bf2, acc[(mh)*4+1][2], 0,0,0); \
    acc[(mh)*4+2][2] = __builtin_amdgcn_mfma_f32_16x16x32_bf16(af2, bf2, acc[(mh)*4+2][2], 0,0,0); \
    acc[(mh)*4+3][2] = __builtin_amdgcn_mfma_f32_16x16x32_bf16(af3, bf2, acc[(mh)*4+3][2], 0,0,0); \
    acc[(mh)*4+0][3] = __builtin_amdgcn_mfma_f32_16x16x32_bf16(af0, bf3, acc[(mh)*4+0][3], 0,0,0); \
    acc[(mh)*4+1][3] = __builtin_amdgcn_mfma_f32_16x16x32_bf16(af1, bf3, acc[(mh)*4+1][3], 0,0,0); \
    acc[(mh)*4+2][3] = __builtin_amdgcn_mfma_f32_16x16x32_bf16(af2, bf3, acc[(mh)*4+2][3], 0,0,0); \
    acc[(mh)*4+3][3] = __builtin_amdgcn_mfma_f32_16x16x32_bf16(af3, bf3, acc[(mh)*4+3][3], 0,0,0); \
} while (0)

#define BARRIER_IN do {                                     \
    __builtin_amdgcn_sched_barrier(0);                      \
    __builtin_amdgcn_s_barrier();                           \
    asm volatile("s_waitcnt lgkmcnt(0)" ::: "memory");      \
    __builtin_amdgcn_sched_barrier(0);                      \
    __builtin_amdgcn_s_setprio(1);                          \
} while (0)

#define BARRIER_OUT do {                                    \
    __builtin_amdgcn_s_setprio(0);                          \
    __builtin_amdgcn_sched_barrier(0);                      \
    __builtin_amdgcn_s_barrier();                           \
    __builtin_amdgcn_sched_barrier(0);                      \
} while (0)

#define WAIT8 asm volatile("s_waitcnt vmcnt(8)" ::: "memory")
#define WAIT4 asm volatile("s_waitcnt vmcnt(4)" ::: "memory")
#define WAIT0 asm volatile("s_waitcnt vmcnt(0)" ::: "memory")
#define WNONE do {} while (0)

// One K-tile = 4 phases. Stage schedule (issue points forced by dbuf liveness):
//   p0 -> t+1 A-khi (buf^1 s2), p1 -> t+1 B-khi (buf^1 s3),
//   p2 -> t+2 A-klo (buf   s0), p3 -> t+2 B-klo (buf   s1).
// Waits: W1 at p1-end (p2 needs t s2,s3 — issued 8 phases ago),
//        W3 at p3-end (next p0 needs t+1 s0,s1 — issued 8 phases ago).
#define KTILE(t, bufc, S0, S1, S2, S3, W1, W3) do {                 \
    /* p0: (mh0,k0) */                                              \
    LOAD_B(0, bufc); LOAD_A(0, 0, bufc);                            \
    if (S0) STAGE(Abase, ((t)+1)*64+32, (bufc)^1, 2);               \
    BARRIER_IN; MFMA_Q(0); BARRIER_OUT;                             \
    /* p1: (mh1,k0) */                                              \
    LOAD_A(1, 0, bufc);                                             \
    if (S1) STAGE(Bbase, ((t)+1)*64+32, (bufc)^1, 3);               \
    W1;                                                             \
    BARRIER_IN; MFMA_Q(1); BARRIER_OUT;                             \
    /* p2: (mh0,k1) */                                              \
    LOAD_B(1, bufc); LOAD_A(0, 1, bufc);                            \
    if (S2) STAGE(Abase, ((t)+2)*64, (bufc), 0);                    \
    BARRIER_IN; MFMA_Q(0); BARRIER_OUT;                             \
    /* p3: (mh1,k1) */                                              \
    LOAD_A(1, 1, bufc);                                             \
    if (S3) STAGE(Bbase, ((t)+2)*64, (bufc), 1);                    \
    W3;                                                             \
    BARRIER_IN; MFMA_Q(1); BARRIER_OUT;                             \
} while (0)

__global__ __launch_bounds__(512, 2) void gemm8_kernel(const __hip_bfloat16* __restrict__ A,
                                                       const __hip_bfloat16* __restrict__ Wb,
                                                       const float* __restrict__ bias,
                                                       float* __restrict__ C) {
    __shared__ __align__(16) __hip_bfloat16 smem[2][4][8192];  // 128 KiB
    char* smemc = (char*)&smem[0][0][0];

    const int tid  = threadIdx.x;
    const int lane = tid & 63;
    const int wid  = tid >> 6;        // 0..7
    const int wr   = wid >> 2;        // 0..1  (M half)
    const int wc   = wid & 3;         // 0..3  (N quarter)

    // T1: XCD-aware swizzle (nwg=512, 512%8==0 -> bijective).
    const int bid = blockIdx.x;
    const int swz = (bid & 7) * 64 + (bid >> 3);
    const int bn  = swz >> 6;         // 0..7
    const int bm  = swz & 63;         // 0..63

    const __hip_bfloat16* Abase = A  + (size_t)bm * 256 * KDIM;
    const __hip_bfloat16* Bbase = Wb + (size_t)bn * 256 * KDIM;

    // --- staging source offsets (inverse-swizzled global, linear LDS dest) ---
    const int c0  = wid * 64 + lane;
    const int c1  = 512 + wid * 64 + lane;
    const int cs0 = c0 ^ ((c0 >> 3) & 7);
    const int cs1 = c1 ^ ((c1 >> 3) & 7);
    const int gOff0 = (cs0 >> 2) * KDIM + (cs0 & 3) * 8;   // elements
    const int gOff1 = (cs1 >> 2) * KDIM + (cs1 & 3) * 8;
    const int lOff0 = wid * 1024;                          // bytes (wave-uniform)
    const int lOff1 = 8192 + wid * 1024;

    // --- swizzled ds_read byte offsets within a 16 KB slot ---
    const int rsel = lane & 15;
    const int kby  = (lane >> 4) * 16;
    int offA[8], offB[4];
#pragma unroll
    for (int m = 0; m < 8; ++m) {
        int a = (wr * 128 + m * 16 + rsel) * 64 + kby;
        offA[m] = a ^ (((a >> 7) & 7) << 4);
    }
#pragma unroll
    for (int n = 0; n < 4; ++n) {
        int a = (wc * 64 + n * 16 + rsel) * 64 + kby;
        offB[n] = a ^ (((a >> 7) & 7) << 4);
    }

    f32x4 acc[8][4];
#pragma unroll
    for (int m = 0; m < 8; ++m)
#pragma unroll
        for (int n = 0; n < 4; ++n)
            acc[m][n] = (f32x4){0.f, 0.f, 0.f, 0.f};

    bf16x8 af0, af1, af2, af3, bf0, bf1, bf2, bf3;

    // --- prologue: stage 6 half-tiles (t0 s0..s3, t1 s0,s1) = 12 loads ---
    STAGE(Abase,  0, 0, 0);
    STAGE(Bbase,  0, 0, 1);
    STAGE(Abase, 32, 0, 2);
    STAGE(Bbase, 32, 0, 3);
    STAGE(Abase, 64, 1, 0);
    STAGE(Bbase, 64, 1, 1);
    WAIT8;                    // t0 s0,s1 landed; 8 stay in flight
    __builtin_amdgcn_sched_barrier(0);
    __builtin_amdgcn_s_barrier();
    __builtin_amdgcn_sched_barrier(0);

    // --- main loop: 32 K-tiles, 2 per iteration ---
    for (int tt = 0; tt < 30; tt += 2) {
        KTILE(tt,     0, 1, 1, 1, 1, WAIT8, WAIT8);
        KTILE(tt + 1, 1, 1, 1, 1, 1, WAIT8, WAIT8);
    }
    KTILE(30, 0, 1, 1, 0, 0, WAIT8, WAIT4);   // stages t31 s2,s3; then only t31 s0..s3 outstanding
    KTILE(31, 1, 0, 0, 0, 0, WAIT0, WNONE);

    // --- epilogue: C/D layout col = lane&15, row = (lane>>4)*4 + r ---
    const int col0 = lane & 15;
    const int r0   = (lane >> 4) * 4;
#pragma unroll
    for (int n = 0; n < 4; ++n) {
        const int cg = bn * 256 + wc * 64 + n * 16 + col0;
        const float bv = bias[cg];
#pragma unroll
        for (int m = 0; m < 8; ++m) {
            const size_t rg = (size_t)bm * 256 + wr * 128 + m * 16 + r0;
#pragma unroll
            for (int r = 0; r < 4; ++r)
                C[(rg + r) * NDIM + cg] = acc[m][n][r] + bv;
        }
    }
}

// ---------------------------------------------------------------------------
// Fallback: naive fused fp32 GEMM (only if workspace too small).
// ---------------------------------------------------------------------------
__global__ void naive_kernel(const float* __restrict__ x,
                             const float* __restrict__ leaf,
                             const float* __restrict__ W,
                             const float* __restrict__ bias,
                             float* __restrict__ out) {
    long idx = (long)blockIdx.x * blockDim.x + threadIdx.x;
    if (idx >= (long)MROWS * NDIM) return;
    int  o = (int)(idx % NDIM);
    long m = idx / NDIM;
    int o2 = o / 169, o1 = (o / 13) % 13, o0 = o % 13;
    float acc = 0.f;
    for (int i = 0; i < KDIM; ++i) {
        int i2 = i / 169, i1 = (i / 13) % 13, i0 = i % 13;
        float d = 0.f;
#pragma unroll
        for (int r = 0; r < RANKD; ++r)
            d += leaf[( r     * LEAFD + o2) * LEAFD + i2]
               * leaf[((4 + r) * LEAFD + o1) * LEAFD + i1]
               * leaf[((8 + r) * LEAFD + o0) * LEAFD + i0];
        acc += x[m * KDIM + i] * (W[(long)o * KDIM + i] + d);
    }
    out[idx] = acc + bias[o];
}

// ---------------------------------------------------------------------------
extern "C" void kernel_launch(void* const* d_in, const int* in_sizes, int n_in,
                              void* d_out, int out_size, void* d_ws, size_t ws_size,
                              hipStream_t stream) {
    const float* x      = (const float*)d_in[0];
    const float* leaf   = (const float*)d_in[1];
    const float* weight = (const float*)d_in[2];
    const float* bias   = (const float*)d_in[3];
    float* out = (float*)d_out;

    const size_t needA = (size_t)MROWS * KDIM * sizeof(__hip_bfloat16);  // 64 MiB
    const size_t needW = (size_t)NDIM  * KDIM * sizeof(__hip_bfloat16);  // 8 MiB

    if (ws_size >= needA + needW) {
        __hip_bfloat16* xb = (__hip_bfloat16*)d_ws;
        __hip_bfloat16* wb = (__hip_bfloat16*)((char*)d_ws + needA);
        build_w_kernel<<<(NDIM * KDIM + 255) / 256, 256, 0, stream>>>(weight, leaf, wb);
        cvt_kernel<<<2048, 256, 0, stream>>>(x, xb, MROWS * KDIM);
        gemm8_kernel<<<(MROWS / 256) * (NDIM / 256), 512, 0, stream>>>(xb, wb, bias, out);
    } else {
        long total = (long)MROWS * NDIM;
        naive_kernel<<<(int)((total + 255) / 256), 256, 0, stream>>>(x, leaf, weight, bias, out);
    }
}